// Round 9
// baseline (422.540 us; speedup 1.0000x reference)
//
#include <hip/hip_runtime.h>

// Chambers, round 15: r13 base (329.6us best: cvt_pk split2, kk-top w2
// prefetch, consumer-side split, CFENCE no-drain, launch_bounds(256,2))
// with L1 REWRITTEN in 32x32x16 MFMA shape. Rationale (validated cycle
// model: 1872 MFMA x 19.4cy x 8 waves = 121us = measured MfmaUtil):
//  - 32x32x16 = 33.8 cy/32768 FLOP vs 2x19.4=38.8 (13% cheaper, m06/m119)
//  - K pads 100->112 (7 steps of 16) instead of 128 (12.5% less L1 work)
//  L1 MFMA: 192x19.4=3725 -> 84x33.8=2839 cy/chamber (-24%, ~-18us pipe).
// tb interface decouples producer/consumer: L1 stores scalar floats via the
// 32x32 C layout (col=lane&31, row=(reg&3)+8*(reg>>2)+4*(lane>>5), guide
// m74/m101); consumer + L2/L3/L4 are r13 byte-identical. kk loop fully
// unrolled so W1-ring slot (i&1, i=kk*7+ks7) is compile-time (rule #20).
// r14 post-mortem: float-up occupancy failed (still 2-wave, -18us ILP) ->
// occupancy closed in all 3 variants (r7 cap-serialize, r10 cap-spill, r14).

typedef unsigned int u32;
typedef __attribute__((ext_vector_type(8))) short bf16x8;
typedef __attribute__((ext_vector_type(4))) float f32x4;
typedef __attribute__((ext_vector_type(16))) float f32x16;

#define RES_DIM 100
#define NCH 6
#define FRAGS_PER_CH 48            // L1: 4nt*7k=28, L2: 4n*4k=16, L3: 2n*2k=4
#define NFRAG (NCH*FRAGS_PER_CH)   // 288
#define WS_BYTES ((size_t)NFRAG*2048)

#define MFMA16 __builtin_amdgcn_mfma_f32_16x16x32_bf16
#define MFMA32 __builtin_amdgcn_mfma_f32_32x32x16_bf16
#define CFENCE() asm volatile("" ::: "memory")

union FragU { bf16x8 v; u32 u[4]; uint4 q; };

// x = hi + lo: hi = RNE-bf16(x), lo = RNE-bf16(x-hi). Packs 2 elems/u32.
__device__ __forceinline__ void split2(float f0, float f1, u32 &hp, u32 &lp){
    u32 h;
    asm("v_cvt_pk_bf16_f32 %0, %1, %2" : "=v"(h) : "v"(f0), "v"(f1));
    float l0 = f0 - __uint_as_float(h << 16);
    float l1 = f1 - __uint_as_float(h & 0xffff0000u);
    u32 l;
    asm("v_cvt_pk_bf16_f32 %0, %1, %2" : "=v"(l) : "v"(l0), "v"(l1));
    hp = h; lp = l;
}

__device__ __forceinline__ float silu1(float x){
    return x * __builtin_amdgcn_rcpf(1.f + __expf(-x));
}
__device__ __forceinline__ f32x4 silu4(f32x4 v){
    f32x4 r; r[0]=silu1(v[0]); r[1]=silu1(v[1]); r[2]=silu1(v[2]); r[3]=silu1(v[3]); return r;
}
__device__ __forceinline__ float sin_rev(float x){ return __builtin_amdgcn_sinf(x*0.15915494309189535f); }

__device__ __forceinline__ void load_frag(const u32* __restrict__ wsb, int frag, int lane,
                                          bf16x8 &h, bf16x8 &l){
    const uint4* p = (const uint4*)(wsb + ((size_t)frag << 9) + (lane << 3));
    FragU H, L; H.q = p[0]; L.q = p[1];
    h = H.v; l = L.v;
}

__device__ __forceinline__ f32x4 triple(f32x4 acc, bf16x8 ah, bf16x8 al, bf16x8 bh, bf16x8 bl){
    acc = MFMA16(ah, bh, acc, 0, 0, 0);
    acc = MFMA16(al, bh, acc, 0, 0, 0);
    acc = MFMA16(ah, bl, acc, 0, 0, 0);
    return acc;
}

// ---------------- prep: split W1..W3 into fragment-lane order ----------------
// L1 frags are 32x32x16 B-operand layout: col n = lane&31 (unit),
// k = (lane>>5)*8 + j. L2/L3 keep the proven 16x16x32 layout.
__global__ void __launch_bounds__(256) prep_kernel(
    const float* __restrict__ W1, const float* __restrict__ W2,
    const float* __restrict__ W3, u32* __restrict__ ws)
{
    const int f = blockIdx.x * 4 + (threadIdx.x >> 6);   // 0..287
    const int lane = threadIdx.x & 63;
    const int c = f / FRAGS_PER_CH, r = f % FRAGS_PER_CH;
    const int n15 = lane & 15, quad = lane >> 4;
    float vals[8];
    if (r < 28) {
        int nt = r / 7, ks7 = r % 7;
        const float* wp = W1 + (size_t)c*128*RES_DIM + (size_t)(nt*32 + (lane & 31))*RES_DIM;
        int kb = ks7*16 + (lane >> 5)*8;
        #pragma unroll
        for (int j=0;j<8;j++){
            int kk = kb + j;
            vals[j] = (kk < RES_DIM) ? wp[kk] : 0.f;
        }
    } else if (r < 44) {
        int rr = r - 28; int n = rr >> 2, k = rr & 3;
        const float* wp = W2 + (size_t)c*64*128 + (size_t)(n*16 + n15)*128;
        #pragma unroll
        for (int j=0;j<8;j++) vals[j] = wp[k*32 + quad*8 + j];
    } else {
        int rr = r - 44; int n = rr >> 1, k = rr & 1;
        const float* wp = W3 + (size_t)c*32*64 + (size_t)(n*16 + n15)*64;
        #pragma unroll
        for (int j=0;j<8;j++) vals[j] = wp[k*32 + quad*8 + j];
    }
    u32 hp[4], lp[4];
    #pragma unroll
    for (int i=0;i<4;i++) split2(vals[2*i], vals[2*i+1], hp[i], lp[i]);
    u32* dst = ws + ((size_t)f << 9) + (lane << 3);
    *(uint4*)(dst)     = make_uint4(hp[0],hp[1],hp[2],hp[3]);
    *(uint4*)(dst + 4) = make_uint4(lp[0],lp[1],lp[2],lp[3]);
}

// ---------------- main MFMA kernel (compiler-fence-synced, drain-free) ----------------
#define TB_STRIDE 36
#define TB_SIZE (32*TB_STRIDE)     // 1152 floats/wave

__global__ void __launch_bounds__(256, 2) chambers_mfma(
    const float* __restrict__ res, const u32* __restrict__ wsb,
    const float* __restrict__ b1, const float* __restrict__ b2,
    const float* __restrict__ b3, const float* __restrict__ W4,
    const float* __restrict__ b4, const float* __restrict__ Cpl,
    float* __restrict__ out, int nsamp)
{
    __shared__ __align__(16) float tb[4][TB_SIZE];   // per-wave transpose buffers
    __shared__ float rawld[4*32*7];                  // per-wave raw[m][c], stride 7

    const int tid  = threadIdx.x;
    const int w    = tid >> 6, lane = tid & 63;
    const int n15  = lane & 15, quad = lane >> 4;
    const int n31  = lane & 31, h32 = lane >> 5;
    const int m_base = (blockIdx.x * 4 + w) * 32;

    // ---- res A-fragments for 32x32x16: row = lane&31, k = (lane>>5)*8+j ----
    // 7 K-steps of 16 (K padded 100->112), split hi/lo, kept for all chambers.
    bf16x8 rAh[7], rAl[7];
    {
        const float* row = res + (size_t)(m_base + n31) * RES_DIM;
        #pragma unroll
        for (int ks7=0; ks7<7; ks7++){
            int kb = ks7*16 + h32*8;
            float v[8];
            if (ks7 < 6){
                float4 A = *(const float4*)(row + kb);
                float4 B = *(const float4*)(row + kb + 4);
                v[0]=A.x; v[1]=A.y; v[2]=A.z; v[3]=A.w;
                v[4]=B.x; v[5]=B.y; v[6]=B.z; v[7]=B.w;
            } else {
                float4 A = make_float4(0.f,0.f,0.f,0.f);
                if (h32 == 0) A = *(const float4*)(row + 96);
                v[0]=A.x; v[1]=A.y; v[2]=A.z; v[3]=A.w;
                v[4]=0.f; v[5]=0.f; v[6]=0.f; v[7]=0.f;
            }
            FragU H, L;
            #pragma unroll
            for (int i=0;i<4;i++) split2(v[2*i], v[2*i+1], H.u[i], L.u[i]);
            rAh[ks7]=H.v; rAl[ks7]=L.v;
        }
    }

    for (int c=0; c<NCH; c++){
        const float* b1c = b1 + c*128;
        const float* b2c = b2 + c*64;
        const float* b3c = b3 + c*32;
        const int fbase = c*FRAGS_PER_CH;

        f32x4 c2[2][4];
        #pragma unroll
        for (int mt=0; mt<2; mt++)
            #pragma unroll
            for (int nt=0; nt<4; nt++){
                float bb = b2c[nt*16 + n15];
                f32x4 t = {bb,bb,bb,bb}; c2[mt][nt] = t;
            }

        // ---- W1 frag ring: 2-deep over the chamber's 28 L1 frags ----
        bf16x8 fh[2], fl[2];
        load_frag(wsb, fbase + 0, lane, fh[0], fl[0]);
        load_frag(wsb, fbase + 1, lane, fh[1], fl[1]);

        // ---- fused L1 (100->128, 32x32x16) + L2 accumulate (16x16x32) ----
        #pragma unroll
        for (int kk=0; kk<4; kk++){
            // prefetch this kk's L2 weight frags (VMEM hides under L1 MFMAs)
            bf16x8 w2h[4], w2l[4];
            #pragma unroll
            for (int nt=0; nt<4; nt++) load_frag(wsb, fbase + 28 + nt*4 + kk, lane, w2h[nt], w2l[nt]);

            // L1 N-tile kk: units kk*32..kk*32+31, one 32x32 tile, 7 K-steps x3
            float bb = b1c[kk*32 + n31];
            f32x16 Dh, Dc1, Dc2;
            #pragma unroll
            for (int i=0;i<16;i++){ Dh[i]=bb; Dc1[i]=0.f; Dc2[i]=0.f; }
            #pragma unroll
            for (int ks7=0; ks7<7; ks7++){
                const int i = kk*7 + ks7;                  // compile-time (kk unrolled)
                bf16x8 bh = fh[i & 1], bl = fl[i & 1];
                if (i < 26) load_frag(wsb, fbase + i + 2, lane, fh[i & 1], fl[i & 1]);
                Dh  = MFMA32(rAh[ks7], bh, Dh,  0,0,0);    // 3 indep chains of 7
                Dc1 = MFMA32(rAl[ks7], bh, Dc1, 0,0,0);
                Dc2 = MFMA32(rAh[ks7], bl, Dc2, 0,0,0);
            }
            // combine + silu + 32x32 C-layout transpose store:
            // col = lane&31 = unit, row = (reg&3)+8*(reg>>2)+4*h32 = sample
            #pragma unroll
            for (int reg=0; reg<16; reg++){
                float d = silu1((Dh[reg] + Dc1[reg]) + Dc2[reg]);
                int m = (reg & 3) + 8*(reg >> 2) + 4*h32;
                tb[w][m*TB_STRIDE + n31] = d;
            }
            CFENCE();   // compiler barrier; wave-local LDS is in-order (no drain)
            bf16x8 a2h[2], a2l[2];
            #pragma unroll
            for (int mt=0; mt<2; mt++){
                const float* qp = &tb[w][(mt*16 + n15)*TB_STRIDE + quad*8];
                float4 A = *(const float4*)qp;
                float4 B = *(const float4*)(qp + 4);
                FragU H, L;
                split2(A.x, A.y, H.u[0], L.u[0]);
                split2(A.z, A.w, H.u[1], L.u[1]);
                split2(B.x, B.y, H.u[2], L.u[2]);
                split2(B.z, B.w, H.u[3], L.u[3]);
                a2h[mt]=H.v; a2l[mt]=L.v;
            }
            CFENCE();   // reads ordered before next kk's writes (in-order LDS)
            #pragma unroll
            for (int nt=0; nt<4; nt++){
                c2[0][nt] = triple(c2[0][nt], a2h[0], a2l[0], w2h[nt], w2l[nt]);
                c2[1][nt] = triple(c2[1][nt], a2h[1], a2l[1], w2h[nt], w2l[nt]);
            }
        }
        #pragma unroll
        for (int mt=0; mt<2; mt++)
            #pragma unroll
            for (int nt=0; nt<4; nt++) c2[mt][nt] = silu4(c2[mt][nt]);

        // ---- L3 (64->32), 16x16x32, r13-exact ----
        f32x4 c3[2][2];
        #pragma unroll
        for (int mt=0; mt<2; mt++)
            #pragma unroll
            for (int nt=0; nt<2; nt++){
                float bb = b3c[nt*16 + n15];
                f32x4 t = {bb,bb,bb,bb}; c3[mt][nt] = t;
            }
        for (int k3=0; k3<2; k3++){
            bf16x8 w3h[2], w3l[2];
            #pragma unroll
            for (int nt=0; nt<2; nt++) load_frag(wsb, fbase + 44 + nt*2 + k3, lane, w3h[nt], w3l[nt]);
            #pragma unroll
            for (int mt=0; mt<2; mt++)
                #pragma unroll
                for (int q2=0; q2<2; q2++)
                    #pragma unroll
                    for (int r=0; r<4; r++)
                        tb[w][(mt*16 + quad*4 + r)*TB_STRIDE + q2*16 + n15] = c2[mt][2*k3+q2][r];
            CFENCE();
            bf16x8 a3h[2], a3l[2];
            #pragma unroll
            for (int mt=0; mt<2; mt++){
                const float* qp = &tb[w][(mt*16 + n15)*TB_STRIDE + quad*8];
                float4 A = *(const float4*)qp;
                float4 B = *(const float4*)(qp + 4);
                FragU H, L;
                split2(A.x, A.y, H.u[0], L.u[0]);
                split2(A.z, A.w, H.u[1], L.u[1]);
                split2(B.x, B.y, H.u[2], L.u[2]);
                split2(B.z, B.w, H.u[3], L.u[3]);
                a3h[mt]=H.v; a3l[mt]=L.v;
            }
            CFENCE();
            #pragma unroll
            for (int nt=0; nt<2; nt++){
                c3[0][nt] = triple(c3[0][nt], a3h[0], a3l[0], w3h[nt], w3l[nt]);
                c3[1][nt] = triple(c3[1][nt], a3h[1], a3l[1], w3h[nt], w3l[nt]);
            }
        }
        #pragma unroll
        for (int mt=0; mt<2; mt++)
            #pragma unroll
            for (int nt=0; nt<2; nt++) c3[mt][nt] = silu4(c3[mt][nt]);

        // ---- L4 (32->1): per-lane partial + 16-lane butterfly reduce ----
        float w4a = W4[c*32 + n15];
        float w4b = W4[c*32 + 16 + n15];
        float bb4 = b4[c];
        #pragma unroll
        for (int mt=0; mt<2; mt++){
            float t0 = c3[mt][0][0]*w4a + c3[mt][1][0]*w4b;
            float t1 = c3[mt][0][1]*w4a + c3[mt][1][1]*w4b;
            float t2 = c3[mt][0][2]*w4a + c3[mt][1][2]*w4b;
            float t3 = c3[mt][0][3]*w4a + c3[mt][1][3]*w4b;
            #pragma unroll
            for (int off=1; off<16; off<<=1){
                t0 += __shfl_xor(t0, off, 64);
                t1 += __shfl_xor(t1, off, 64);
                t2 += __shfl_xor(t2, off, 64);
                t3 += __shfl_xor(t3, off, 64);
            }
            if (n15 == 0){
                int mb = w*32 + mt*16 + quad*4;
                rawld[(mb+0)*7 + c] = t0 + bb4;
                rawld[(mb+1)*7 + c] = t1 + bb4;
                rawld[(mb+2)*7 + c] = t2 + bb4;
                rawld[(mb+3)*7 + c] = t3 + bb4;
            }
        }
    }
    __threadfence_block();     // rawld writes (lanes n15==0) visible wave-wide

    // ---- sigmoid + coupling; lanes 0..31 own one sample (32..63 duplicate) ----
    const int m = lane & 31;
    float rw[6], a[6];
    #pragma unroll
    for (int j=0;j<6;j++){
        rw[j] = rawld[(w*32 + m)*7 + j];
        a[j]  = __builtin_amdgcn_rcpf(1.f + __expf(-rw[j]));
    }
    const float dec[6] = {0.9f,0.93f,0.85f,0.97f,0.88f,0.94f};
    float C[6][6];
    #pragma unroll
    for (int i=0;i<6;i++)
        #pragma unroll
        for (int j=0;j<6;j++) C[i][j] = Cpl[i*6+j];
    #pragma unroll
    for (int it=0; it<5; it++){
        #pragma unroll
        for (int j=0;j<6;j++) a[j] *= dec[j];
        float nz[6];
        #pragma unroll
        for (int i=0;i<6;i++){
            float sum = 0.f;
            #pragma unroll
            for (int j=0;j<6;j++) sum += sin_rev(a[j]-a[i]) * C[i][j];
            nz[i] = a[i] + 0.02f*sum;
        }
        #pragma unroll
        for (int i=0;i<6;i++) a[i] = fminf(fmaxf(nz[i],0.f),1.f);
    }
    if (lane < 32){
        size_t s = (size_t)m_base + m;
        #pragma unroll
        for (int j=0;j<6;j++) out[s*6 + j] = a[j];
        size_t rb = (size_t)nsamp*6 + s*6;
        #pragma unroll
        for (int j=0;j<6;j++) out[rb + j] = rw[j];
    }
}

// ---------------- fallback: proven round-3 VALU kernel ----------------
__global__ void __launch_bounds__(256, 2) chambers_fb(
    const float* __restrict__ res, const float* __restrict__ W1, const float* __restrict__ b1,
    const float* __restrict__ W2, const float* __restrict__ b2,
    const float* __restrict__ W3, const float* __restrict__ b3,
    const float* __restrict__ W4, const float* __restrict__ b4,
    const float* __restrict__ Cpl, float* __restrict__ out, int nsamp)
{
    __shared__ float w2t[128*64];
    __shared__ float h3buf[256][33];
    __shared__ float rawbuf[256][7];
    const int tid = threadIdx.x;
    const long long s = (long long)blockIdx.x * 256 + tid;
    float rf[RES_DIM];
    {
        const float4* rp = (const float4*)(res + s*RES_DIM);
        #pragma unroll
        for (int i=0;i<25;i++){
            float4 v = rp[i];
            rf[4*i+0]=v.x; rf[4*i+1]=v.y; rf[4*i+2]=v.z; rf[4*i+3]=v.w;
        }
    }
    for (int c=0;c<6;c++){
        __syncthreads();
        {
            const float* w2c = W2 + c*64*128;
            for (int k=tid; k<64*128; k+=256){
                int o = k >> 7, u = k & 127;
                w2t[u*64 + o] = w2c[k];
            }
        }
        __syncthreads();
        const float* w1c = W1 + c*128*RES_DIM;
        const float* b1c = b1 + c*128;
        const float* b2c = b2 + c*64;
        float h2a[64];
        #pragma unroll
        for (int o=0;o<64;o++) h2a[o] = b2c[o];
        for (int u=0; u<128; u+=2){
            const float4* wa = (const float4*)(w1c + u*RES_DIM);
            const float4* wb = wa + 25;
            float a0=0.f,a1=0.f,a2=0.f,a3=0.f;
            #pragma unroll
            for (int i=0;i<25;i++){
                float4 va=wa[i], vb=wb[i];
                a0 = fmaf(va.x, rf[4*i+0], a0); a0 = fmaf(va.y, rf[4*i+1], a0);
                a2 = fmaf(va.z, rf[4*i+2], a2); a2 = fmaf(va.w, rf[4*i+3], a2);
                a1 = fmaf(vb.x, rf[4*i+0], a1); a1 = fmaf(vb.y, rf[4*i+1], a1);
                a3 = fmaf(vb.z, rf[4*i+2], a3); a3 = fmaf(vb.w, rf[4*i+3], a3);
            }
            float hh0 = silu1(a0+a2+b1c[u]);
            float hh1 = silu1(a1+a3+b1c[u+1]);
            const float* wr0 = &w2t[u*64];
            const float* wr1 = &w2t[(u+1)*64];
            #pragma unroll
            for (int o=0;o<64;o+=4){
                float4 va = *(const float4*)(wr0+o);
                float4 vb = *(const float4*)(wr1+o);
                h2a[o+0] = fmaf(va.x, hh0, fmaf(vb.x, hh1, h2a[o+0]));
                h2a[o+1] = fmaf(va.y, hh0, fmaf(vb.y, hh1, h2a[o+1]));
                h2a[o+2] = fmaf(va.z, hh0, fmaf(vb.z, hh1, h2a[o+2]));
                h2a[o+3] = fmaf(va.w, hh0, fmaf(vb.w, hh1, h2a[o+3]));
            }
        }
        #pragma unroll
        for (int o=0;o<64;o++) h2a[o] = silu1(h2a[o]);
        {
            const float* w3c = W3 + c*32*64;
            const float* b3c = b3 + c*32;
            for (int p=0; p<32; p+=2){
                const float4* wa = (const float4*)(w3c + p*64);
                const float4* wb = wa + 16;
                float a0=0.f,a1=0.f,a2=0.f,a3=0.f;
                #pragma unroll
                for (int k=0;k<16;k++){
                    float4 va=wa[k], vb=wb[k];
                    a0 = fmaf(va.x, h2a[4*k+0], a0); a0 = fmaf(va.y, h2a[4*k+1], a0);
                    a2 = fmaf(va.z, h2a[4*k+2], a2); a2 = fmaf(va.w, h2a[4*k+3], a2);
                    a1 = fmaf(vb.x, h2a[4*k+0], a1); a1 = fmaf(vb.y, h2a[4*k+1], a1);
                    a3 = fmaf(vb.z, h2a[4*k+2], a3); a3 = fmaf(vb.w, h2a[4*k+3], a3);
                }
                h3buf[tid][p]   = silu1(a0+a2+b3c[p]);
                h3buf[tid][p+1] = silu1(a1+a3+b3c[p+1]);
            }
        }
        {
            const float4* w4p = (const float4*)(W4 + c*32);
            float a0=0.f, a1=0.f;
            #pragma unroll
            for (int k=0;k<8;k++){
                float4 v = w4p[k];
                a0 = fmaf(v.x, h3buf[tid][4*k+0], a0);
                a1 = fmaf(v.y, h3buf[tid][4*k+1], a1);
                a0 = fmaf(v.z, h3buf[tid][4*k+2], a0);
                a1 = fmaf(v.w, h3buf[tid][4*k+3], a1);
            }
            rawbuf[tid][c] = a0+a1+b4[c];
        }
    }
    float a[6], rw[6];
    #pragma unroll
    for (int j=0;j<6;j++){ rw[j]=rawbuf[tid][j]; a[j]=__builtin_amdgcn_rcpf(1.f+__expf(-rw[j])); }
    const float dec[6] = {0.9f,0.93f,0.85f,0.97f,0.88f,0.94f};
    float C[6][6];
    #pragma unroll
    for (int i=0;i<6;i++)
        #pragma unroll
        for (int j=0;j<6;j++) C[i][j]=Cpl[i*6+j];
    #pragma unroll
    for (int it=0; it<5; it++){
        #pragma unroll
        for (int j=0;j<6;j++) a[j]*=dec[j];
        float nz[6];
        #pragma unroll
        for (int i=0;i<6;i++){
            float sum=0.f;
            #pragma unroll
            for (int j=0;j<6;j++) sum += sin_rev(a[j]-a[i]) * C[i][j];
            nz[i]=a[i]+0.02f*sum;
        }
        #pragma unroll
        for (int i=0;i<6;i++) a[i]=fminf(fmaxf(nz[i],0.f),1.f);
    }
    long long ob = s*6;
    #pragma unroll
    for (int j=0;j<6;j++) out[ob+j] = a[j];
    long long rb = (long long)nsamp*6 + ob;
    #pragma unroll
    for (int j=0;j<6;j++) out[rb+j] = rw[j];
}

extern "C" void kernel_launch(void* const* d_in, const int* in_sizes, int n_in,
                              void* d_out, int out_size, void* d_ws, size_t ws_size,
                              hipStream_t stream) {
    const float* res = (const float*)d_in[0];
    const float* W1  = (const float*)d_in[1];
    const float* b1  = (const float*)d_in[2];
    const float* W2  = (const float*)d_in[3];
    const float* b2  = (const float*)d_in[4];
    const float* W3  = (const float*)d_in[5];
    const float* b3  = (const float*)d_in[6];
    const float* W4  = (const float*)d_in[7];
    const float* b4  = (const float*)d_in[8];
    const float* Cpl = (const float*)d_in[9];
    float* out = (float*)d_out;
    int nsamp = in_sizes[0] / RES_DIM;     // 262144

    if (ws_size >= WS_BYTES) {
        u32* ws = (u32*)d_ws;
        prep_kernel<<<NFRAG/4, 256, 0, stream>>>(W1, W2, W3, ws);
        chambers_mfma<<<nsamp/128, 256, 0, stream>>>(res, ws, b1, b2, b3, W4, b4, Cpl, out, nsamp);
    } else {
        chambers_fb<<<nsamp/256, 256, 0, stream>>>(res, W1, b1, W2, b2, W3, b3, W4, b4, Cpl, out, nsamp);
    }
}